// Round 8
// baseline (611.401 us; speedup 1.0000x reference)
//
#include <hip/hip_runtime.h>

// Problem constants (fixed by the reference's setup_inputs)
#define G_     32
#define N_     2048
#define D_     128
#define K_     1024
#define EPER_  16384

// ---------------------------------------------------------------------------
// Single fused kernel, 256 blocks x 1024 threads (16 waves + 17 KB LDS + low
// VGPR -> all 256 blocks co-resident on 256 CUs, so per-graph spin barriers
// cannot deadlock). Block (g,sb) = (bid>>3, bid&7). Phases, separated by
// per-graph 8-block flag barriers (device-scope release/acquire atomics +
// __threadfence for data visibility across XCD L2s, per Guideline 16):
//  A: dot products p/base/s2 for own 256-node slice
//  B: [wait ndone==8] LDS edge-agg of own 2048-edge slice -> part[g*8+sb]
//  C: [wait adone==8] graph keys in LDS (deterministic fixed-order partial
//     merge -> identical across the graph's 8 blocks), T=4-tiled rank count
//     with wave-uniform broadcast LDS reads, new_idx write, and direct
//     scatter of x_out rows + new_batch for surviving nodes
//  D: [wait rdone==8] edge re-index + mask for own edge slice (L2-warm)
// ---------------------------------------------------------------------------
__global__ __launch_bounds__(1024) void fused_pool(
    const float* __restrict__ x,
    const int*   __restrict__ src,
    const int*   __restrict__ dst,
    const float* __restrict__ w_rel,
    const float* __restrict__ b_rel_p,
    const float* __restrict__ w_root,
    const float* __restrict__ w_lin,
    const float* __restrict__ b_lin_p,
    float* __restrict__ p,
    float* __restrict__ base,
    float* __restrict__ s2,
    float* __restrict__ part,
    int*   __restrict__ new_idx,
    int*   __restrict__ flags,      // [0..31]=ndone, [32..63]=adone, [64..95]=rdone
    float* __restrict__ out_x,
    float* __restrict__ out_b,
    float* __restrict__ out_e0,
    float* __restrict__ out_e1,
    float* __restrict__ out_m)
{
    __shared__ unsigned long long keys_s[N_];   // 16 KB (aliased as agg in B)
    __shared__ int   cnt_s[256];
    __shared__ float sc_s[256];

    const int tid = threadIdx.x;
    const int g   = blockIdx.x >> 3;
    const int sb  = blockIdx.x & 7;

    int* ndone = flags;
    int* adone = flags + 32;
    int* rdone = flags + 64;

    // ---------------- Phase A: dots for own 256-node slice ----------------
    {
        const int lane = tid & 63;
        const int c    = lane & 31;
        const int wv   = tid >> 6;              // wave 0..15
        float4 wr = ((const float4*)w_rel)[c];
        float4 wo = ((const float4*)w_root)[c];
        float4 wl = ((const float4*)w_lin)[c];
        float brel = b_rel_p[0], blin = b_lin_p[0];
        const int slice0 = g * N_ + sb * 256;
        #pragma unroll
        for (int it = 0; it < 8; ++it) {
            int node = slice0 + it * 32 + wv * 2 + (lane >> 5);
            float4 xv = ((const float4*)(x + (size_t)node * D_))[c];
            float pr = xv.x * wr.x + xv.y * wr.y + xv.z * wr.z + xv.w * wr.w;
            float po = xv.x * wo.x + xv.y * wo.y + xv.z * wo.z + xv.w * wo.w;
            float pl = xv.x * wl.x + xv.y * wl.y + xv.z * wl.z + xv.w * wl.w;
            #pragma unroll
            for (int off = 16; off; off >>= 1) {
                pr += __shfl_xor(pr, off);
                po += __shfl_xor(po, off);
                pl += __shfl_xor(pl, off);
            }
            if (c == 0) {
                p[node]    = pr;
                base[node] = po + brel;
                s2[node]   = pl + blin;
            }
        }
    }
    __threadfence();
    __syncthreads();
    if (tid == 0)
        __hip_atomic_fetch_add(&ndone[g], 1, __ATOMIC_RELEASE, __HIP_MEMORY_SCOPE_AGENT);

    // ---------------- Phase B: wait dots; agg own edge slice ----------------
    if (tid == 0) {
        while (__hip_atomic_load(&ndone[g], __ATOMIC_ACQUIRE, __HIP_MEMORY_SCOPE_AGENT) < 8)
            __builtin_amdgcn_s_sleep(8);
    }
    __syncthreads();
    __threadfence();
    {
        float* agg = (float*)keys_s;
        agg[tid]        = 0.0f;
        agg[tid + 1024] = 0.0f;
        __syncthreads();
        int e0 = g * EPER_ + sb * 2048 + tid;
        const float* gp = p + (size_t)g * N_;
        atomicAdd(&agg[dst[e0] & (N_ - 1)],        gp[src[e0] & (N_ - 1)]);
        atomicAdd(&agg[dst[e0 + 1024] & (N_ - 1)], gp[src[e0 + 1024] & (N_ - 1)]);
        __syncthreads();
        float* op = part + ((size_t)g * 8 + sb) * N_;
        op[tid]        = agg[tid];
        op[tid + 1024] = agg[tid + 1024];
    }
    __threadfence();
    __syncthreads();
    if (tid == 0)
        __hip_atomic_fetch_add(&adone[g], 1, __ATOMIC_RELEASE, __HIP_MEMORY_SCOPE_AGENT);

    // ---------------- Phase C: wait agg; keys + rank + gather ----------------
    if (tid == 0) {
        while (__hip_atomic_load(&adone[g], __ATOMIC_ACQUIRE, __HIP_MEMORY_SCOPE_AGENT) < 8)
            __builtin_amdgcn_s_sleep(8);
    }
    __syncthreads();
    __threadfence();
    {
        for (int i = tid; i < N_; i += 1024) {
            const float* pp = part + (size_t)g * 8 * N_ + i;
            float a = 0.0f;
            #pragma unroll
            for (int s = 0; s < 8; ++s) a += pp[(size_t)s * N_];
            int node = g * N_ + i;
            float sc = fmaxf(base[node] + a, s2[node]);
            if ((i >> 8) == sb) sc_s[i & 255] = sc;
            unsigned u = __float_as_uint(sc);
            u ^= ((int)u < 0) ? 0xFFFFFFFFu : 0x80000000u;
            keys_s[i] = ((unsigned long long)u << 32) | (unsigned)(N_ - 1 - i);
        }
        if (tid < 256) cnt_s[tid] = 0;
        __syncthreads();

        // rank count: thread (iq, js) holds 4 i-keys in VGPRs, scans a 128-j
        // slice; js = tid>>6 is wave-uniform -> pure LDS broadcast reads.
        int iq = tid & 63;
        int js = tid >> 6;
        int ibase = sb * 256 + iq * 4;
        unsigned long long ki0 = keys_s[ibase + 0];
        unsigned long long ki1 = keys_s[ibase + 1];
        unsigned long long ki2 = keys_s[ibase + 2];
        unsigned long long ki3 = keys_s[ibase + 3];
        const ulonglong2* k2 = (const ulonglong2*)keys_s + js * 64;
        int c0 = 0, c1 = 0, c2 = 0, c3 = 0;
        #pragma unroll 8
        for (int j = 0; j < 64; ++j) {
            ulonglong2 kk = k2[j];          // same addr across the wave
            c0 += (kk.x > ki0) + (kk.y > ki0);
            c1 += (kk.x > ki1) + (kk.y > ki1);
            c2 += (kk.x > ki2) + (kk.y > ki2);
            c3 += (kk.x > ki3) + (kk.y > ki3);
        }
        atomicAdd(&cnt_s[iq * 4 + 0], c0);
        atomicAdd(&cnt_s[iq * 4 + 1], c1);
        atomicAdd(&cnt_s[iq * 4 + 2], c2);
        atomicAdd(&cnt_s[iq * 4 + 3], c3);
        __syncthreads();

        if (tid < 256) {
            int rank = cnt_s[tid];
            int node = g * N_ + sb * 256 + tid;
            new_idx[node] = (rank < K_) ? (g * K_ + rank) : -1;
        }
        __syncthreads();

        // scatter surviving rows (16B/lane coalesced row copy)
        int grp = tid >> 5;
        int l32 = tid & 31;
        #pragma unroll
        for (int it = 0; it < 8; ++it) {
            int s = it * 32 + grp;
            int rank = cnt_s[s];
            if (rank < K_) {
                int node = g * N_ + sb * 256 + s;
                int row  = g * K_ + rank;
                float tz = tanhf(sc_s[s]);
                float4 xv = ((const float4*)(x + (size_t)node * D_))[l32];
                ((float4*)(out_x + (size_t)row * D_))[l32] =
                    make_float4(xv.x * tz, xv.y * tz, xv.z * tz, xv.w * tz);
                if (l32 == 0) out_b[row] = (float)g;
            }
        }
    }
    __threadfence();
    __syncthreads();
    if (tid == 0)
        __hip_atomic_fetch_add(&rdone[g], 1, __ATOMIC_RELEASE, __HIP_MEMORY_SCOPE_AGENT);

    // ---------------- Phase D: wait ranks; edge re-index + mask ----------------
    if (tid == 0) {
        while (__hip_atomic_load(&rdone[g], __ATOMIC_ACQUIRE, __HIP_MEMORY_SCOPE_AGENT) < 8)
            __builtin_amdgcn_s_sleep(8);
    }
    __syncthreads();
    __threadfence();
    {
        int e0 = g * EPER_ + sb * 2048 + tid;
        #pragma unroll
        for (int t = 0; t < 2; ++t) {
            int e = e0 + t * 1024;
            int ns = new_idx[src[e]];
            int nd = new_idx[dst[e]];
            bool m = (ns >= 0) && (nd >= 0);
            out_e0[e] = m ? (float)ns : 0.0f;
            out_e1[e] = m ? (float)nd : 0.0f;
            out_m[e]  = m ? 1.0f : 0.0f;
        }
    }
}

extern "C" void kernel_launch(void* const* d_in, const int* in_sizes, int n_in,
                              void* d_out, int out_size, void* d_ws, size_t ws_size,
                              hipStream_t stream)
{
    const float* x      = (const float*)d_in[0];
    const int*   ei     = (const int*)d_in[1];
    const float* w_rel  = (const float*)d_in[3];
    const float* b_rel  = (const float*)d_in[4];
    const float* w_root = (const float*)d_in[5];
    const float* w_lin  = (const float*)d_in[6];
    const float* b_lin  = (const float*)d_in[7];
    float* out = (float*)d_out;

    const int n_nodes = in_sizes[0] / D_;   // 65536
    const int E       = in_sizes[1] / 2;    // 524288
    const int* src = ei;
    const int* dst = ei + E;

    // workspace layout
    float* p     = (float*)d_ws;
    float* base  = p + n_nodes;
    float* s2    = base + n_nodes;
    float* part  = s2 + n_nodes;                        // 32*8*2048 f32 = 2 MB
    int*   new_idx = (int*)(part + (size_t)G_ * 8 * N_);
    int*   flags   = new_idx + n_nodes;                 // 96 ints

    // output offsets (elements, f32)
    const size_t offEI = (size_t)G_ * K_ * D_;      // 4194304
    const size_t offM  = offEI + 2 * (size_t)E;     // 5242880
    const size_t offB  = offM + (size_t)E;          // 5767168

    float* out_x  = out;
    float* out_e0 = out + offEI;
    float* out_e1 = out + offEI + E;
    float* out_m  = out + offM;
    float* out_b  = out + offB;

    hipMemsetAsync(flags, 0, 96 * sizeof(int), stream);
    fused_pool<<<256, 1024, 0, stream>>>(
        x, src, dst, w_rel, b_rel, w_root, w_lin, b_lin,
        p, base, s2, part, new_idx, flags,
        out_x, out_b, out_e0, out_e1, out_m);
}

// Round 11
// 121.082 us; speedup vs baseline: 5.0495x; 5.0495x over previous
//
#include <hip/hip_runtime.h>

// Problem constants (fixed by the reference's setup_inputs)
#define G_     32
#define N_     2048
#define D_     128
#define K_     1024
#define EPER_  16384

// ---------------------------------------------------------------------------
// Kernel 1: per-node dot products. One wave = 2 nodes (32 lanes each, float4
// per lane -> 16B/lane coalesced). Butterfly reduce within each 32-lane half.
// ---------------------------------------------------------------------------
__global__ __launch_bounds__(256) void node_dots(
    const float* __restrict__ x,
    const float* __restrict__ w_rel,
    const float* __restrict__ w_root,
    const float* __restrict__ w_lin,
    const float* __restrict__ b_rel_p,
    const float* __restrict__ b_lin_p,
    float* __restrict__ p,
    float* __restrict__ base,
    float* __restrict__ s2,
    int n_nodes)
{
    int wave = (blockIdx.x * 256 + threadIdx.x) >> 6;
    int lane = threadIdx.x & 63;
    int node = wave * 2 + (lane >> 5);
    int c    = lane & 31;
    if (node >= n_nodes) return;

    float4 xv = ((const float4*)(x + (size_t)node * D_))[c];
    float4 wr = ((const float4*)w_rel)[c];
    float4 wo = ((const float4*)w_root)[c];
    float4 wl = ((const float4*)w_lin)[c];

    float pr = xv.x * wr.x + xv.y * wr.y + xv.z * wr.z + xv.w * wr.w;
    float po = xv.x * wo.x + xv.y * wo.y + xv.z * wo.z + xv.w * wo.w;
    float pl = xv.x * wl.x + xv.y * wl.y + xv.z * wl.z + xv.w * wl.w;

    #pragma unroll
    for (int off = 16; off; off >>= 1) {
        pr += __shfl_xor(pr, off);
        po += __shfl_xor(po, off);
        pl += __shfl_xor(pl, off);
    }
    if (c == 0) {
        p[node]    = pr;
        base[node] = po + b_rel_p[0];
        s2[node]   = pl + b_lin_p[0];
    }
}

// ---------------------------------------------------------------------------
// Kernel 2: edge aggregation, 8 sub-blocks per graph, each accumulating its
// 2048-edge slice into a private LDS copy -> global partial. Exactly ONE
// agg partial-set per graph (all rank blocks must later see identical keys;
// atomicAdd fp-order varies, so agg must not be computed redundantly).
// ---------------------------------------------------------------------------
__global__ __launch_bounds__(1024) void agg_partial(
    const int* __restrict__ src, const int* __restrict__ dst,
    const float* __restrict__ p, float* __restrict__ part)
{
    __shared__ float agg[N_];
    int g = blockIdx.x >> 3;
    int s = blockIdx.x & 7;
    agg[threadIdx.x]        = 0.0f;
    agg[threadIdx.x + 1024] = 0.0f;
    __syncthreads();

    int e0 = g * EPER_ + s * 2048 + threadIdx.x;
    int e1 = e0 + 1024;
    const float* gp = p + (size_t)g * N_;
    atomicAdd(&agg[dst[e0] & (N_ - 1)], gp[src[e0] & (N_ - 1)]);
    atomicAdd(&agg[dst[e1] & (N_ - 1)], gp[src[e1] & (N_ - 1)]);
    __syncthreads();

    float* op = part + ((size_t)g * 8 + s) * N_;
    op[threadIdx.x]        = agg[threadIdx.x];
    op[threadIdx.x + 1024] = agg[threadIdx.x + 1024];
}

// ---------------------------------------------------------------------------
// Kernel 3 (score+key+rank+GATHER fused): 8 blocks/graph x 1024 threads.
// Each block computes ALL 2048 keys of its graph into LDS (deterministic
// fixed-order partial merge -> identical keys across the graph's 8 blocks),
// ranks its 256-node i-slice via the T=4-tiled wave-uniform-broadcast count,
// writes new_idx, and directly scatters x_out rows + new_batch for its
// surviving nodes (row = g*K + rank, scale = tanh(score)).
// ---------------------------------------------------------------------------
__global__ __launch_bounds__(1024) void topk_gather(
    const float* __restrict__ part,
    const float* __restrict__ base, const float* __restrict__ s2,
    const float* __restrict__ x,
    int* __restrict__ new_idx,
    float* __restrict__ out_x, float* __restrict__ out_b)
{
    __shared__ unsigned long long keys_s[N_];   // 16 KB
    __shared__ int   cnt_s[256];
    __shared__ float sc_s[256];
    const int tid = threadIdx.x;
    const int g   = blockIdx.x >> 3;
    const int sb  = blockIdx.x & 7;

    for (int i = tid; i < N_; i += 1024) {
        const float* pp = part + (size_t)g * 8 * N_ + i;
        float a = 0.0f;
        #pragma unroll
        for (int s = 0; s < 8; ++s) a += pp[(size_t)s * N_];
        int node = g * N_ + i;
        float sc = fmaxf(base[node] + a, s2[node]);
        if ((i >> 8) == sb) sc_s[i & 255] = sc;
        unsigned u = __float_as_uint(sc);
        u ^= ((int)u < 0) ? 0xFFFFFFFFu : 0x80000000u;
        keys_s[i] = ((unsigned long long)u << 32) | (unsigned)(N_ - 1 - i);
    }
    if (tid < 256) cnt_s[tid] = 0;
    __syncthreads();

    // rank count: thread (iq, js) holds 4 i-keys in VGPRs, scans a 128-j
    // slice; js = tid>>6 is wave-uniform -> all 64 lanes read the SAME
    // ulonglong2 LDS address (pure broadcast, no bank conflicts).
    {
        int iq = tid & 63;
        int js = tid >> 6;
        int ibase = sb * 256 + iq * 4;
        unsigned long long ki0 = keys_s[ibase + 0];
        unsigned long long ki1 = keys_s[ibase + 1];
        unsigned long long ki2 = keys_s[ibase + 2];
        unsigned long long ki3 = keys_s[ibase + 3];
        const ulonglong2* k2 = (const ulonglong2*)keys_s + js * 64;
        int c0 = 0, c1 = 0, c2 = 0, c3 = 0;
        #pragma unroll 8
        for (int j = 0; j < 64; ++j) {
            ulonglong2 kk = k2[j];          // same addr across the wave
            c0 += (kk.x > ki0) + (kk.y > ki0);
            c1 += (kk.x > ki1) + (kk.y > ki1);
            c2 += (kk.x > ki2) + (kk.y > ki2);
            c3 += (kk.x > ki3) + (kk.y > ki3);
        }
        atomicAdd(&cnt_s[iq * 4 + 0], c0);
        atomicAdd(&cnt_s[iq * 4 + 1], c1);
        atomicAdd(&cnt_s[iq * 4 + 2], c2);
        atomicAdd(&cnt_s[iq * 4 + 3], c3);
    }
    __syncthreads();

    if (tid < 256) {
        int rank = cnt_s[tid];
        int node = g * N_ + sb * 256 + tid;
        new_idx[node] = (rank < K_) ? (g * K_ + rank) : -1;
    }
    __syncthreads();

    // scatter surviving rows: 32 groups of 32 lanes; group handles slice
    // nodes s = grp, grp+32, ... (8 each). 16B/lane coalesced row copy.
    {
        int grp = tid >> 5;
        int l32 = tid & 31;
        #pragma unroll
        for (int it = 0; it < 8; ++it) {
            int s = it * 32 + grp;
            int rank = cnt_s[s];
            if (rank < K_) {
                int node = g * N_ + sb * 256 + s;
                int row  = g * K_ + rank;
                float tz = tanhf(sc_s[s]);
                float4 xv = ((const float4*)(x + (size_t)node * D_))[l32];
                ((float4*)(out_x + (size_t)row * D_))[l32] =
                    make_float4(xv.x * tz, xv.y * tz, xv.z * tz, xv.w * tz);
                if (l32 == 0) out_b[row] = (float)g;
            }
        }
    }
}

// ---------------------------------------------------------------------------
// Kernel 4: edge re-index + mask, 4 edges/thread via int4 loads / float4
// stores (E % 4 == 0). Pure BW; fewer instructions than 1 edge/thread.
// ---------------------------------------------------------------------------
__global__ __launch_bounds__(256) void edge_out_kernel(
    const int* __restrict__ src, const int* __restrict__ dst,
    const int* __restrict__ new_idx,
    float* __restrict__ out_e0,
    float* __restrict__ out_e1,
    float* __restrict__ out_m, int E)
{
    int q = blockIdx.x * 256 + threadIdx.x;        // quad index
    if (q * 4 >= E) return;
    int4 s4 = ((const int4*)src)[q];
    int4 d4 = ((const int4*)dst)[q];

    int ns0 = new_idx[s4.x], nd0 = new_idx[d4.x];
    int ns1 = new_idx[s4.y], nd1 = new_idx[d4.y];
    int ns2 = new_idx[s4.z], nd2 = new_idx[d4.z];
    int ns3 = new_idx[s4.w], nd3 = new_idx[d4.w];

    bool m0 = (ns0 >= 0) && (nd0 >= 0);
    bool m1 = (ns1 >= 0) && (nd1 >= 0);
    bool m2 = (ns2 >= 0) && (nd2 >= 0);
    bool m3 = (ns3 >= 0) && (nd3 >= 0);

    ((float4*)out_e0)[q] = make_float4(m0 ? (float)ns0 : 0.0f,
                                       m1 ? (float)ns1 : 0.0f,
                                       m2 ? (float)ns2 : 0.0f,
                                       m3 ? (float)ns3 : 0.0f);
    ((float4*)out_e1)[q] = make_float4(m0 ? (float)nd0 : 0.0f,
                                       m1 ? (float)nd1 : 0.0f,
                                       m2 ? (float)nd2 : 0.0f,
                                       m3 ? (float)nd3 : 0.0f);
    ((float4*)out_m)[q]  = make_float4(m0 ? 1.0f : 0.0f,
                                       m1 ? 1.0f : 0.0f,
                                       m2 ? 1.0f : 0.0f,
                                       m3 ? 1.0f : 0.0f);
}

extern "C" void kernel_launch(void* const* d_in, const int* in_sizes, int n_in,
                              void* d_out, int out_size, void* d_ws, size_t ws_size,
                              hipStream_t stream)
{
    const float* x      = (const float*)d_in[0];
    const int*   ei     = (const int*)d_in[1];
    const float* w_rel  = (const float*)d_in[3];
    const float* b_rel  = (const float*)d_in[4];
    const float* w_root = (const float*)d_in[5];
    const float* w_lin  = (const float*)d_in[6];
    const float* b_lin  = (const float*)d_in[7];
    float* out = (float*)d_out;

    const int n_nodes = in_sizes[0] / D_;   // 65536
    const int E       = in_sizes[1] / 2;    // 524288
    const int* src = ei;
    const int* dst = ei + E;

    // workspace layout
    float* p     = (float*)d_ws;
    float* base  = p + n_nodes;
    float* s2    = base + n_nodes;
    float* part  = s2 + n_nodes;                        // 32*8*2048 f32 = 2 MB
    int*   new_idx = (int*)(part + (size_t)G_ * 8 * N_);

    // output offsets (elements, f32)
    const size_t offEI = (size_t)G_ * K_ * D_;      // 4194304
    const size_t offM  = offEI + 2 * (size_t)E;     // 5242880
    const size_t offB  = offM + (size_t)E;          // 5767168

    node_dots<<<n_nodes / 8, 256, 0, stream>>>(
        x, w_rel, w_root, w_lin, b_rel, b_lin, p, base, s2, n_nodes);
    agg_partial<<<G_ * 8, 1024, 0, stream>>>(src, dst, p, part);
    topk_gather<<<G_ * 8, 1024, 0, stream>>>(
        part, base, s2, x, new_idx, out, out + offB);
    edge_out_kernel<<<(E / 4 + 255) / 256, 256, 0, stream>>>(
        src, dst, new_idx, out + offEI, out + offEI + E, out + offM, E);
}